// Round 6
// baseline (74.486 us; speedup 1.0000x reference)
//
#include <hip/hip_runtime.h>
#include <math.h>

#define WIDTH 8192
#define NROW  2048          // B*C = 16*128
#define T4    (WIDTH / 4)   // float4 slots per row = 2048

// ---------------------------------------------------------------------------
// Probe: decide how the boolean mask was marshalled.
//   flag = 0 : int32 per element, 1 : byte per element, 2 : float32 per elem
// ---------------------------------------------------------------------------
__global__ void detect_mask_kind(const unsigned* __restrict__ mw,
                                 int* __restrict__ flag) {
    int lid = threadIdx.x;  // one wave of 64
    int isbyte = 0, isfloat = 0;
#pragma unroll
    for (int j = 0; j < 4; ++j) {
        unsigned w = mw[lid * 4 + j];
        if (w == 0x3F800000u)      isfloat = 1;
        else if (w > 1u)           isbyte  = 1;
    }
    unsigned long long bf = __ballot(isfloat != 0);
    unsigned long long bb = __ballot(isbyte != 0);
    if (lid == 0) flag[0] = bf ? 2 : (bb ? 1 : 0);
}

// compare-exchange: a=min, b=max
#define CE(a, b) { float _lo = fminf(a, b); float _hi = fmaxf(a, b); (a) = _lo; (b) = _hi; }

// median of merge(sorted A[4], sorted tail T[3]) at index k=(n-1)>>1 (k<=3).
// merged[k] = min over i+j=k of max(A[i], T[j]); T[-1]/A[-1] = -inf, T[3] = +inf.
#define MEDIAN(A0,A1,A2,A3, T0,T1,T2, N, DST) {                                   \
    float _M0 = fminf(A0, T0);                                                    \
    float _M1 = fminf(fminf(A1, T1), fmaxf(A0, T0));                              \
    float _M2 = fminf(fminf(A2, T2), fminf(fmaxf(A1, T0), fmaxf(A0, T1)));        \
    float _M3 = fminf(fminf(A3, fmaxf(A2, T0)),                                   \
                      fminf(fmaxf(A1, T1), fmaxf(A0, T2)));                       \
    int   _k  = ((N) - 1) >> 1;                                                   \
    float _md = (_k <= 0) ? _M0 : (_k == 1) ? _M1 : (_k == 2) ? _M2 : _M3;        \
    (DST) = (_md == INF) ? __builtin_nanf("") : _md; }

// 4 bytes (each 0 or 1) -> 4 bits (b0|b1<<1|b2<<2|b3<<3). Carry-free.
__device__ __forceinline__ unsigned nib4(unsigned w) {
    return ((w & 0x01010101u) * 0x01020408u) >> 24;
}

__launch_bounds__(256)
__global__ void mmp_kernel(const float* __restrict__ x,
                           const void* __restrict__ mask,
                           const int* __restrict__ flag,
                           float* __restrict__ out) {
    const int bid   = blockIdx.x;
    const int row   = bid >> 3;                 // 8 blocks per row
    const int chunk = bid & 7;
    const int t     = chunk * 256 + threadIdx.x;   // float4 slot (4 outputs)
    const long rb4  = (long)row * T4;

    // ---- x: 12 values covering original indices 4t-4 .. 4t+7 (coalesced) ----
    const float4* x4 = (const float4*)x + rb4;
    const float4 Z4  = make_float4(0.f, 0.f, 0.f, 0.f);
    float4 X0 = (t > 0)      ? x4[t - 1] : Z4;
    float4 X1 = x4[t];
    float4 X2 = (t < T4 - 1) ? x4[t + 1] : Z4;

    // ---- optimistic byte-layout mask loads (real marshalling), in flight
    //      before the flag value is needed; always in-bounds for any kind ----
    const unsigned* mwp = (const unsigned*)mask + rb4;
    unsigned g0 = (t > 0)      ? mwp[t - 1] : 0u;
    unsigned g1 = mwp[t];
    unsigned g2 = (t < T4 - 1) ? mwp[t + 1] : 0u;

    const int kind = flag[0];                   // uniform branch
    unsigned bits;                              // validity bits, j = 0..11
    if (kind == 1) {                            // byte mask (numpy bool_, 0/1)
        bits = nib4(g0) | (nib4(g1) << 4) | (nib4(g2) << 8);
    } else if (kind == 0) {                     // int32 mask
        const int4* m4 = (const int4*)mask + rb4;
        const int4 ZI = make_int4(0, 0, 0, 0);
        int4 I0 = (t > 0)      ? m4[t - 1] : ZI;
        int4 I1 = m4[t];
        int4 I2 = (t < T4 - 1) ? m4[t + 1] : ZI;
        bits = (unsigned)((I0.x != 0)        | ((I0.y != 0) << 1) |
                          ((I0.z != 0) << 2) | ((I0.w != 0) << 3) |
                          ((I1.x != 0) << 4) | ((I1.y != 0) << 5) |
                          ((I1.z != 0) << 6) | ((I1.w != 0) << 7) |
                          ((I2.x != 0) << 8) | ((I2.y != 0) << 9) |
                          ((I2.z != 0) <<10) | ((I2.w != 0) <<11));
    } else {                                    // float32 mask
        const float4* m4 = (const float4*)mask + rb4;
        float4 F0 = (t > 0)      ? m4[t - 1] : Z4;
        float4 F1 = m4[t];
        float4 F2 = (t < T4 - 1) ? m4[t + 1] : Z4;
        bits = (unsigned)((F0.x != 0.f)        | ((F0.y != 0.f) << 1) |
                          ((F0.z != 0.f) << 2) | ((F0.w != 0.f) << 3) |
                          ((F1.x != 0.f) << 4) | ((F1.y != 0.f) << 5) |
                          ((F1.z != 0.f) << 6) | ((F1.w != 0.f) << 7) |
                          ((F2.x != 0.f) << 8) | ((F2.y != 0.f) << 9) |
                          ((F2.z != 0.f) <<10) | ((F2.w != 0.f) <<11));
    }

    const float INF = __builtin_inff();
    const float xv[12] = { X0.x, X0.y, X0.z, X0.w,
                           X1.x, X1.y, X1.z, X1.w,
                           X2.x, X2.y, X2.z, X2.w };

    // masked values for window elements j=1..10 (element j = index 4t-4+j)
    float m[11];
#pragma unroll
    for (int j = 1; j <= 10; ++j) m[j] = (bits & (1u << j)) ? xv[j] : INF;

    // ---- shared sorted pairs ----
    float p0 = m[2], p1 = m[3]; CE(p0, p1);     // pair {2,3}
    float q0 = m[8], q1 = m[9]; CE(q0, q1);     // pair {8,9}

    // ---- core = sorted {m4,m5,m6,m7} (common to all 4 windows) ----
    float A0 = m[4], A1 = m[5]; CE(A0, A1);
    float A2 = m[6], A3 = m[7]; CE(A2, A3);
    CE(A0, A2); CE(A1, A3); CE(A1, A2);

    // ---- sorted tails (2 CE each, reusing shared pairs) ----
    float u0 = m[1], u1 = p0, u2 = p1;  CE(u0, u1); CE(u1, u2);   // W0 {1,2,3}
    float v0 = p0,   v1 = p1, v2 = m[8]; CE(v1, v2); CE(v0, v1);  // W1 {2,3,8}
    float w0 = m[3], w1 = q0, w2 = q1;  CE(w0, w1); CE(w1, w2);   // W2 {3,8,9}
    float y0 = q0,   y1 = q1, y2 = m[10]; CE(y1, y2); CE(y0, y1); // W3 {8,9,10}

    // ---- valid counts ----
    const int n0 = __popc((bits >> 1) & 0x7Fu);
    const int n1 = __popc((bits >> 2) & 0x7Fu);
    const int n2 = __popc((bits >> 3) & 0x7Fu);
    const int n3 = __popc((bits >> 4) & 0x7Fu);

    // ---- medians ----
    float o_0, o_1, o_2, o_3;
    MEDIAN(A0, A1, A2, A3, u0, u1, u2, n0, o_0);
    MEDIAN(A0, A1, A2, A3, v0, v1, v2, n1, o_1);
    MEDIAN(A0, A1, A2, A3, w0, w1, w2, n2, o_2);
    MEDIAN(A0, A1, A2, A3, y0, y1, y2, n3, o_3);

    float4* o4 = (float4*)out + rb4;
    o4[t] = make_float4(o_0, o_1, o_2, o_3);     // plain cached store (NT removed)
}

extern "C" void kernel_launch(void* const* d_in, const int* in_sizes, int n_in,
                              void* d_out, int out_size, void* d_ws, size_t ws_size,
                              hipStream_t stream) {
    const float* x    = (const float*)d_in[0];
    const void*  mask = d_in[1];
    int*   flag = (int*)d_ws;
    float* outp = (float*)d_out;

    detect_mask_kind<<<1, 64, 0, stream>>>((const unsigned*)mask, flag);
    mmp_kernel<<<NROW * 8, 256, 0, stream>>>(x, mask, flag, outp);
}

// Round 7
// 68.496 us; speedup vs baseline: 1.0874x; 1.0874x over previous
//
#include <hip/hip_runtime.h>
#include <math.h>

#define WIDTH 8192
#define NROW  2048          // B*C = 16*128
#define T4    (WIDTH / 4)   // float4 slots per row = 2048

// ---------------------------------------------------------------------------
// Probe: decide how the boolean mask was marshalled.
//   flag = 0 : int32 per element, 1 : byte per element, 2 : float32 per elem
// ---------------------------------------------------------------------------
__global__ void detect_mask_kind(const unsigned* __restrict__ mw,
                                 int* __restrict__ flag) {
    int lid = threadIdx.x;  // one wave of 64
    int isbyte = 0, isfloat = 0;
#pragma unroll
    for (int j = 0; j < 4; ++j) {
        unsigned w = mw[lid * 4 + j];
        if (w == 0x3F800000u)      isfloat = 1;
        else if (w > 1u)           isbyte  = 1;
    }
    unsigned long long bf = __ballot(isfloat != 0);
    unsigned long long bb = __ballot(isbyte != 0);
    if (lid == 0) flag[0] = bf ? 2 : (bb ? 1 : 0);
}

// compare-exchange: a=min, b=max
#define CE(a, b) { float _lo = fminf(a, b); float _hi = fmaxf(a, b); (a) = _lo; (b) = _hi; }

// median of merge(sorted A[4], sorted tail T[3]) at index k=(n-1)>>1 (k<=3).
// merged[k] = min over i+j=k of max(A[i], T[j]); T[-1]/A[-1] = -inf, T[3] = +inf.
#define MEDIAN(A0,A1,A2,A3, T0,T1,T2, N, DST) {                                   \
    float _M0 = fminf(A0, T0);                                                    \
    float _M1 = fminf(fminf(A1, T1), fmaxf(A0, T0));                              \
    float _M2 = fminf(fminf(A2, T2), fminf(fmaxf(A1, T0), fmaxf(A0, T1)));        \
    float _M3 = fminf(fminf(A3, fmaxf(A2, T0)),                                   \
                      fminf(fmaxf(A1, T1), fmaxf(A0, T2)));                       \
    int   _k  = ((N) - 1) >> 1;                                                   \
    float _md = (_k <= 0) ? _M0 : (_k == 1) ? _M1 : (_k == 2) ? _M2 : _M3;        \
    (DST) = (_md == INF) ? __builtin_nanf("") : _md; }

// 4 bytes (each 0 or 1) -> 4 bits (b0|b1<<1|b2<<2|b3<<3). Carry-free.
__device__ __forceinline__ unsigned nib4(unsigned w) {
    return ((w & 0x01010101u) * 0x01020408u) >> 24;
}

__launch_bounds__(256)
__global__ void mmp_kernel(const float* __restrict__ x,
                           const void* __restrict__ mask,
                           const int* __restrict__ flag,
                           float* __restrict__ out) {
    const int bid   = blockIdx.x;
    const int row   = bid >> 3;                 // 8 blocks per row
    const int chunk = bid & 7;
    const int tid   = threadIdx.x;
    const int t     = chunk * 256 + tid;        // float4 slot (4 outputs)
    const int lane  = tid & 63;
    const long rb4  = (long)row * T4;

    const float4*   x4  = (const float4*)x + rb4;
    const unsigned* mwp = (const unsigned*)mask + rb4;
    const float4    Z4  = make_float4(0.f, 0.f, 0.f, 0.f);

    // ---- own loads only: 1 float4 + 1 mask word per thread (each cache
    //      line touched exactly once per row pass) ----
    float4   X1 = x4[t];
    unsigned g1 = mwp[t];

    // ---- halo from adjacent lanes (slot t±1 lives in lane±1); wave-edge
    //      lanes fetch their halo directly ----
    float4 Xp, Xn;
    Xp.x = __shfl_up(X1.x, 1);   Xp.y = __shfl_up(X1.y, 1);
    Xp.z = __shfl_up(X1.z, 1);   Xp.w = __shfl_up(X1.w, 1);
    unsigned gp = __shfl_up(g1, 1);
    Xn.x = __shfl_down(X1.x, 1); Xn.y = __shfl_down(X1.y, 1);
    Xn.z = __shfl_down(X1.z, 1); Xn.w = __shfl_down(X1.w, 1);
    unsigned gn = __shfl_down(g1, 1);
    if (lane == 0) {
        Xp = (t > 0)      ? x4[t - 1]  : Z4;
        gp = (t > 0)      ? mwp[t - 1] : 0u;
    }
    if (lane == 63) {
        Xn = (t < T4 - 1) ? x4[t + 1]  : Z4;
        gn = (t < T4 - 1) ? mwp[t + 1] : 0u;
    }

    const int kind = flag[0];                   // uniform branch
    unsigned bits;                              // validity bits, j = 0..11
    if (kind == 1) {                            // byte mask (numpy bool_) — hot
        bits = nib4(gp) | (nib4(g1) << 4) | (nib4(gn) << 8);
    } else if (kind == 0) {                     // int32 mask — cold path
        const int4* m4 = (const int4*)mask + rb4;
        const int4 ZI = make_int4(0, 0, 0, 0);
        int4 I0 = (t > 0)      ? m4[t - 1] : ZI;
        int4 I1 = m4[t];
        int4 I2 = (t < T4 - 1) ? m4[t + 1] : ZI;
        bits = (unsigned)((I0.x != 0)        | ((I0.y != 0) << 1) |
                          ((I0.z != 0) << 2) | ((I0.w != 0) << 3) |
                          ((I1.x != 0) << 4) | ((I1.y != 0) << 5) |
                          ((I1.z != 0) << 6) | ((I1.w != 0) << 7) |
                          ((I2.x != 0) << 8) | ((I2.y != 0) << 9) |
                          ((I2.z != 0) <<10) | ((I2.w != 0) <<11));
    } else {                                    // float32 mask — cold path
        const float4* m4 = (const float4*)mask + rb4;
        float4 F0 = (t > 0)      ? m4[t - 1] : Z4;
        float4 F1 = m4[t];
        float4 F2 = (t < T4 - 1) ? m4[t + 1] : Z4;
        bits = (unsigned)((F0.x != 0.f)        | ((F0.y != 0.f) << 1) |
                          ((F0.z != 0.f) << 2) | ((F0.w != 0.f) << 3) |
                          ((F1.x != 0.f) << 4) | ((F1.y != 0.f) << 5) |
                          ((F1.z != 0.f) << 6) | ((F1.w != 0.f) << 7) |
                          ((F2.x != 0.f) << 8) | ((F2.y != 0.f) << 9) |
                          ((F2.z != 0.f) <<10) | ((F2.w != 0.f) <<11));
    }

    const float INF = __builtin_inff();
    const float xv[12] = { Xp.x, Xp.y, Xp.z, Xp.w,
                           X1.x, X1.y, X1.z, X1.w,
                           Xn.x, Xn.y, Xn.z, Xn.w };

    // masked values for window elements j=1..10 (element j = index 4t-4+j)
    float m[11];
#pragma unroll
    for (int j = 1; j <= 10; ++j) m[j] = (bits & (1u << j)) ? xv[j] : INF;

    // ---- shared sorted pairs ----
    float p0 = m[2], p1 = m[3]; CE(p0, p1);     // pair {2,3}
    float q0 = m[8], q1 = m[9]; CE(q0, q1);     // pair {8,9}

    // ---- core = sorted {m4,m5,m6,m7} (common to all 4 windows) ----
    float A0 = m[4], A1 = m[5]; CE(A0, A1);
    float A2 = m[6], A3 = m[7]; CE(A2, A3);
    CE(A0, A2); CE(A1, A3); CE(A1, A2);

    // ---- sorted tails (2 CE each, reusing shared pairs) ----
    float u0 = m[1], u1 = p0, u2 = p1;  CE(u0, u1); CE(u1, u2);   // W0 {1,2,3}
    float v0 = p0,   v1 = p1, v2 = m[8]; CE(v1, v2); CE(v0, v1);  // W1 {2,3,8}
    float w0 = m[3], w1 = q0, w2 = q1;  CE(w0, w1); CE(w1, w2);   // W2 {3,8,9}
    float y0 = q0,   y1 = q1, y2 = m[10]; CE(y1, y2); CE(y0, y1); // W3 {8,9,10}

    // ---- valid counts ----
    const int n0 = __popc((bits >> 1) & 0x7Fu);
    const int n1 = __popc((bits >> 2) & 0x7Fu);
    const int n2 = __popc((bits >> 3) & 0x7Fu);
    const int n3 = __popc((bits >> 4) & 0x7Fu);

    // ---- medians ----
    float o_0, o_1, o_2, o_3;
    MEDIAN(A0, A1, A2, A3, u0, u1, u2, n0, o_0);
    MEDIAN(A0, A1, A2, A3, v0, v1, v2, n1, o_1);
    MEDIAN(A0, A1, A2, A3, w0, w1, w2, n2, o_2);
    MEDIAN(A0, A1, A2, A3, y0, y1, y2, n3, o_3);

    float4* o4 = (float4*)out + rb4;
    o4[t] = make_float4(o_0, o_1, o_2, o_3);
}

extern "C" void kernel_launch(void* const* d_in, const int* in_sizes, int n_in,
                              void* d_out, int out_size, void* d_ws, size_t ws_size,
                              hipStream_t stream) {
    const float* x    = (const float*)d_in[0];
    const void*  mask = d_in[1];
    int*   flag = (int*)d_ws;
    float* outp = (float*)d_out;

    detect_mask_kind<<<1, 64, 0, stream>>>((const unsigned*)mask, flag);
    mmp_kernel<<<NROW * 8, 256, 0, stream>>>(x, mask, flag, outp);
}

// Round 9
// 67.756 us; speedup vs baseline: 1.0993x; 1.0109x over previous
//
#include <hip/hip_runtime.h>
#include <math.h>

#define WIDTH 8192
#define NROW  2048          // B*C = 16*128
#define T4    (WIDTH / 4)   // float4 slots per row = 2048

// compare-exchange: a=min, b=max
#define CE(a, b) { float _lo = fminf(a, b); float _hi = fmaxf(a, b); (a) = _lo; (b) = _hi; }

// One window: independent full 7-sort (high ILP — 4 of these run in parallel).
// Window I covers elements I+1 .. I+7 of xv[]; bits hold validity per element.
// Only the bottom-4 sorted positions are consumed; the compiler DCEs the rest.
#define WINDOW(I, DST) {                                                      \
    const unsigned wb = (bits >> ((I) + 1)) & 0x7Fu;                          \
    const int n = __popc(wb);                                                 \
    float v0 = (wb & 1u)  ? xv[(I) + 1] : INF;                                \
    float v1 = (wb & 2u)  ? xv[(I) + 2] : INF;                                \
    float v2 = (wb & 4u)  ? xv[(I) + 3] : INF;                                \
    float v3 = (wb & 8u)  ? xv[(I) + 4] : INF;                                \
    float v4 = (wb & 16u) ? xv[(I) + 5] : INF;                                \
    float v5 = (wb & 32u) ? xv[(I) + 6] : INF;                                \
    float v6 = (wb & 64u) ? xv[(I) + 7] : INF;                                \
    CE(v0, v1); CE(v2, v3); CE(v4, v5);   /* round 0 */                       \
    CE(v1, v2); CE(v3, v4); CE(v5, v6);   /* round 1 */                       \
    CE(v0, v1); CE(v2, v3); CE(v4, v5);   /* round 2 */                       \
    CE(v1, v2); CE(v3, v4); CE(v5, v6);   /* round 3 */                       \
    CE(v0, v1); CE(v2, v3); CE(v4, v5);   /* round 4 */                       \
    CE(v1, v2); CE(v3, v4); CE(v5, v6);   /* round 5 */                       \
    CE(v0, v1); CE(v2, v3);               /* round 6 (v4,v5 dead) */          \
    const int k = (n - 1) >> 1;                                               \
    float med = (k == 0) ? v0 : (k == 1) ? v1 : (k == 2) ? v2 : v3;           \
    (DST) = (n == 0) ? __builtin_nanf("") : med; }

__launch_bounds__(256)
__global__ void mmp_kernel(const float* __restrict__ x,
                           const int* __restrict__ mask,
                           float* __restrict__ out) {
    const int bid   = blockIdx.x;
    const int row   = bid >> 3;                 // 8 blocks per row
    const int chunk = bid & 7;
    const int t     = chunk * 256 + threadIdx.x;   // float4 slot (4 outputs)
    const long rb4  = (long)row * T4;

    // ---- x: 12 values covering original indices 4t-4 .. 4t+7 (coalesced) ----
    const float4* x4 = (const float4*)x + rb4;
    const float4 Z4  = make_float4(0.f, 0.f, 0.f, 0.f);
    float4 X0 = (t > 0)      ? x4[t - 1] : Z4;
    float4 X1 = x4[t];
    float4 X2 = (t < T4 - 1) ? x4[t + 1] : Z4;

    // ---- int32 mask (confirmed by r8's byte-path NaN failure) ----
    const int4* m4 = (const int4*)mask + rb4;
    const int4  ZI = make_int4(0, 0, 0, 0);
    int4 I0 = (t > 0)      ? m4[t - 1] : ZI;
    int4 I1 = m4[t];
    int4 I2 = (t < T4 - 1) ? m4[t + 1] : ZI;
    const unsigned bits =
        (unsigned)((I0.x != 0)        | ((I0.y != 0) << 1) |
                   ((I0.z != 0) << 2) | ((I0.w != 0) << 3) |
                   ((I1.x != 0) << 4) | ((I1.y != 0) << 5) |
                   ((I1.z != 0) << 6) | ((I1.w != 0) << 7) |
                   ((I2.x != 0) << 8) | ((I2.y != 0) << 9) |
                   ((I2.z != 0) <<10) | ((I2.w != 0) <<11));

    const float INF = __builtin_inff();
    const float xv[12] = { X0.x, X0.y, X0.z, X0.w,
                           X1.x, X1.y, X1.z, X1.w,
                           X2.x, X2.y, X2.z, X2.w };

    // ---- 4 independent windows (ILP=4 hides VALU dep-latency + mem wait) ----
    float o_0, o_1, o_2, o_3;
    WINDOW(0, o_0);
    WINDOW(1, o_1);
    WINDOW(2, o_2);
    WINDOW(3, o_3);

    float4* o4 = (float4*)out + rb4;
    o4[t] = make_float4(o_0, o_1, o_2, o_3);
}

extern "C" void kernel_launch(void* const* d_in, const int* in_sizes, int n_in,
                              void* d_out, int out_size, void* d_ws, size_t ws_size,
                              hipStream_t stream) {
    const float* x    = (const float*)d_in[0];
    const int*   mask = (const int*)d_in[1];
    float*       outp = (float*)d_out;

    mmp_kernel<<<NROW * 8, 256, 0, stream>>>(x, mask, outp);
}

// Round 10
// 43.903 us; speedup vs baseline: 1.6966x; 1.5433x over previous
//
#include <hip/hip_runtime.h>
#include <math.h>

#define WIDTH 8192
#define NROW  2048                    // B*C = 16*128
#define T4    2048                    // float4 slots per row
#define NSLOT (NROW * T4)             // 4,194,304 flat slots
#define NBLK  2048
#define NTHR  256
#define SSTEP (NBLK * NTHR)           // 524,288 slots per sweep
#define ITERS (NSLOT / SSTEP)         // 8 iterations per thread

// compare-exchange: a=min, b=max
#define CE(a, b) { float _lo = fminf(a, b); float _hi = fmaxf(a, b); (a) = _lo; (b) = _hi; }

// One window: independent full 7-sort (high ILP — 4 run in parallel).
// Window I covers elements I+1 .. I+7 of xv[]; bits hold validity per element.
#define WINDOW(I, DST) {                                                      \
    const unsigned wb = (bits >> ((I) + 1)) & 0x7Fu;                          \
    const int n = __popc(wb);                                                 \
    float v0 = (wb & 1u)  ? xv[(I) + 1] : INF;                                \
    float v1 = (wb & 2u)  ? xv[(I) + 2] : INF;                                \
    float v2 = (wb & 4u)  ? xv[(I) + 3] : INF;                                \
    float v3 = (wb & 8u)  ? xv[(I) + 4] : INF;                                \
    float v4 = (wb & 16u) ? xv[(I) + 5] : INF;                                \
    float v5 = (wb & 32u) ? xv[(I) + 6] : INF;                                \
    float v6 = (wb & 64u) ? xv[(I) + 7] : INF;                                \
    CE(v0, v1); CE(v2, v3); CE(v4, v5);   /* round 0 */                       \
    CE(v1, v2); CE(v3, v4); CE(v5, v6);   /* round 1 */                       \
    CE(v0, v1); CE(v2, v3); CE(v4, v5);   /* round 2 */                       \
    CE(v1, v2); CE(v3, v4); CE(v5, v6);   /* round 3 */                       \
    CE(v0, v1); CE(v2, v3); CE(v4, v5);   /* round 4 */                       \
    CE(v1, v2); CE(v3, v4); CE(v5, v6);   /* round 5 */                       \
    CE(v0, v1); CE(v2, v3);               /* round 6 (v4,v5 dead) */          \
    const int k = (n - 1) >> 1;                                               \
    float med = (k == 0) ? v0 : (k == 1) ? v1 : (k == 2) ? v2 : v3;           \
    (DST) = (n == 0) ? __builtin_nanf("") : med; }

__launch_bounds__(NTHR)
__global__ void mmp_kernel(const float* __restrict__ x,
                           const int* __restrict__ mask,
                           float* __restrict__ out) {
    const float4* x4 = (const float4*)x;
    const int4*   m4 = (const int4*)mask;
    float4*       o4 = (float4*)out;

    const int   sid0 = blockIdx.x * NTHR + threadIdx.x;   // first flat slot
    const float4 Z4  = make_float4(0.f, 0.f, 0.f, 0.f);
    const int4   ZI  = make_int4(0, 0, 0, 0);
    const float  INF = __builtin_inff();

    // ---- current tile (A) — prologue load for iteration 0 ----
    float4 XA0, XA1, XA2; int4 MA0, MA1, MA2;
    {
        const int s = sid0;
        const int t = s & (T4 - 1);
        XA0 = (t > 0)      ? x4[s - 1] : Z4;
        XA1 = x4[s];
        XA2 = (t < T4 - 1) ? x4[s + 1] : Z4;
        MA0 = (t > 0)      ? m4[s - 1] : ZI;
        MA1 = m4[s];
        MA2 = (t < T4 - 1) ? m4[s + 1] : ZI;
    }

#pragma unroll
    for (int it = 0; it < ITERS; ++it) {
        const int s = sid0 + it * SSTEP;

        // ---- prefetch next tile (B) BEFORE computing current (A):
        //      ~800 compute cycles hide the load latency ----
        float4 XB0 = Z4, XB1 = Z4, XB2 = Z4;
        int4   MB0 = ZI, MB1 = ZI, MB2 = ZI;
        if (it < ITERS - 1) {
            const int sn = s + SSTEP;
            const int tn = sn & (T4 - 1);
            XB0 = (tn > 0)      ? x4[sn - 1] : Z4;
            XB1 = x4[sn];
            XB2 = (tn < T4 - 1) ? x4[sn + 1] : Z4;
            MB0 = (tn > 0)      ? m4[sn - 1] : ZI;
            MB1 = m4[sn];
            MB2 = (tn < T4 - 1) ? m4[sn + 1] : ZI;
        }

        // ---- compute tile A ----
        const unsigned bits =
            (unsigned)((MA0.x != 0)        | ((MA0.y != 0) << 1) |
                       ((MA0.z != 0) << 2) | ((MA0.w != 0) << 3) |
                       ((MA1.x != 0) << 4) | ((MA1.y != 0) << 5) |
                       ((MA1.z != 0) << 6) | ((MA1.w != 0) << 7) |
                       ((MA2.x != 0) << 8) | ((MA2.y != 0) << 9) |
                       ((MA2.z != 0) <<10) | ((MA2.w != 0) <<11));
        const float xv[12] = { XA0.x, XA0.y, XA0.z, XA0.w,
                               XA1.x, XA1.y, XA1.z, XA1.w,
                               XA2.x, XA2.y, XA2.z, XA2.w };

        float o_0, o_1, o_2, o_3;
        WINDOW(0, o_0);
        WINDOW(1, o_1);
        WINDOW(2, o_2);
        WINDOW(3, o_3);
        o4[s] = make_float4(o_0, o_1, o_2, o_3);

        // ---- rotate B -> A (static, fully unrolled — stays in registers) ----
        XA0 = XB0; XA1 = XB1; XA2 = XB2;
        MA0 = MB0; MA1 = MB1; MA2 = MB2;
    }
}

extern "C" void kernel_launch(void* const* d_in, const int* in_sizes, int n_in,
                              void* d_out, int out_size, void* d_ws, size_t ws_size,
                              hipStream_t stream) {
    const float* x    = (const float*)d_in[0];
    const int*   mask = (const int*)d_in[1];
    float*       outp = (float*)d_out;

    mmp_kernel<<<NBLK, NTHR, 0, stream>>>(x, mask, outp);
}